// Round 11
// baseline (162.741 us; speedup 1.0000x reference)
//
#include <hip/hip_runtime.h>
#include <hip/hip_bf16.h>

#define LL 4096
#define DD 512
#define BB 8
#define KSEL 41

typedef __attribute__((ext_vector_type(4))) float f32x4;
typedef __attribute__((ext_vector_type(8))) short short8;

__device__ __forceinline__ ushort f2bf(float x) {
  __hip_bfloat16 h = __float2bfloat16(x);
  return *reinterpret_cast<ushort*>(&h);
}

__device__ __forceinline__ void g2lds16(const void* g, void* l) {
  __builtin_amdgcn_global_load_lds(
      (const __attribute__((address_space(1))) unsigned int*)g,
      (__attribute__((address_space(3))) unsigned int*)l, 16, 0, 0);
}

// ------- K1: Wvo^T (bf16) = (Wv @ Wo)^T -------
__global__ __launch_bounds__(256) void k_wvot(const float* __restrict__ Wv,
                                              const float* __restrict__ Wo,
                                              ushort* __restrict__ WT) {
  __shared__ float wv[8][512];
  int tid = threadIdx.x;
  int c = blockIdx.x * 256 + tid;
  int j0 = blockIdx.y * 8;
  for (int t = tid; t < 8 * 512; t += 256)
    wv[t >> 9][t & 511] = Wv[(size_t)(j0 + (t >> 9)) * DD + (t & 511)];
  __syncthreads();
  float acc[8] = {0, 0, 0, 0, 0, 0, 0, 0};
  for (int m = 0; m < DD; ++m) {
    float wo = Wo[(size_t)m * DD + c];
#pragma unroll
    for (int j = 0; j < 8; ++j) acc[j] += wv[j][m] * wo;
  }
  ushort4 o0, o1;
  o0.x = f2bf(acc[0]); o0.y = f2bf(acc[1]); o0.z = f2bf(acc[2]); o0.w = f2bf(acc[3]);
  o1.x = f2bf(acc[4]); o1.y = f2bf(acc[5]); o1.z = f2bf(acc[6]); o1.w = f2bf(acc[7]);
  *(ushort4*)&WT[(size_t)c * DD + j0] = o0;
  *(ushort4*)&WT[(size_t)c * DD + j0 + 4] = o1;
}

// ---- K2: FUSED {P = v @ Wvo (blocks 0..1023)} || {colsum q,k (blocks 1024..1535)} ----
union SmemF {
  struct { ushort lA[128 * 64]; ushort lB[128 * 64]; } g;  // 32 KB (Pgemm)
  float red[4][512];                                       // 8 KB (colsum)
};

__global__ __launch_bounds__(256) void k_fused(
    const float* __restrict__ q, const float* __restrict__ kk,
    const float* __restrict__ v, const ushort* __restrict__ WvoT,
    ushort* __restrict__ P, float* __restrict__ qpart, float* __restrict__ kpart) {
  __shared__ SmemF sm;
  int bid = blockIdx.x;
  int tid = threadIdx.x;

  if (bid < 1024) {
    // ---------- Pgemm: 128x128 tile, BK=64, verified k_gemm structure ----------
    int bcol = (bid & 3) * 128;
    int brow = ((bid >> 2) & 31) * 128;
    int b = bid >> 7;
    const float* vb = v + (size_t)b * LL * DD;
    int lane = tid & 63, wid = tid >> 6;
    int wr = wid >> 1, wc = wid & 1;
    int r15 = lane & 15, g = lane >> 4;
    f32x4 acc[4][4] = {};
    for (int k0 = 0; k0 < DD; k0 += 64) {
      // stage A: v f32 -> bf16 chunks, same swizzled layout as lB
#pragma unroll
      for (int it = 0; it < 4; ++it) {
        int e = it * 256 + tid;
        int row = e >> 3, chl = e & 7;
        const float* src = vb + (size_t)(brow + row) * DD + k0 + ((chl ^ (row & 7)) * 8);
        f32x4 x = *(const f32x4*)src;
        f32x4 y = *(const f32x4*)(src + 4);
        union { ushort us[8]; short8 s; } pk;
        pk.us[0] = f2bf(x[0]); pk.us[1] = f2bf(x[1]);
        pk.us[2] = f2bf(x[2]); pk.us[3] = f2bf(x[3]);
        pk.us[4] = f2bf(y[0]); pk.us[5] = f2bf(y[1]);
        pk.us[6] = f2bf(y[2]); pk.us[7] = f2bf(y[3]);
        *(short8*)&sm.g.lA[e * 8] = pk.s;
      }
      // stage B: WvoT via global_load_lds (inverse-swizzled source)
#pragma unroll
      for (int it = 0; it < 4; ++it) {
        int ch = it * 256 + tid;
        int row = ch >> 3;
        int clg = (ch & 7) ^ (row & 7);
        g2lds16(WvoT + (size_t)(bcol + row) * DD + k0 + clg * 8, &sm.g.lB[ch * 8]);
      }
      asm volatile("s_waitcnt vmcnt(0)" ::: "memory");
      __syncthreads();
#pragma unroll
      for (int ks = 0; ks < 2; ++ks) {
        int kc = ks * 4 + g;
        short8 av[4], bv[4];
#pragma unroll
        for (int m = 0; m < 4; ++m) {
          int row = wr * 64 + m * 16 + r15;
          av[m] = *(const short8*)&sm.g.lA[(row * 8 + (kc ^ (row & 7))) * 8];
          int col = wc * 64 + m * 16 + r15;
          bv[m] = *(const short8*)&sm.g.lB[(col * 8 + (kc ^ (col & 7))) * 8];
        }
#pragma unroll
        for (int m = 0; m < 4; ++m)
#pragma unroll
          for (int n = 0; n < 4; ++n)
            acc[m][n] = __builtin_amdgcn_mfma_f32_16x16x32_bf16(av[m], bv[n], acc[m][n], 0, 0, 0);
      }
      __syncthreads();
    }
    ushort* Pb = P + ((size_t)b * LL + brow) * DD + bcol;
#pragma unroll
    for (int n = 0; n < 4; ++n) {
      int col = wc * 64 + n * 16 + r15;
#pragma unroll
      for (int m = 0; m < 4; ++m) {
        int row = wr * 64 + m * 16 + g * 4;
#pragma unroll
        for (int r = 0; r < 4; ++r)
          Pb[(size_t)(row + r) * DD + col] = f2bf(acc[m][n][r]);
      }
    }
    return;
  }

  // ---------- colsum: streaming NT reads + in-block reduce ----------
  int cbid = bid - 1024;
  int which = cbid & 1, lc = (cbid >> 1) & 31, b = cbid >> 6;
  const float* src = which ? kk : q;
  float* part = which ? kpart : qpart;
  int lane = tid & 63, w = tid >> 6;
  int c8 = lane * 8;
  const float* p = src + ((size_t)b * LL + (size_t)lc * 128 + w * 32) * DD + c8;
  float a0 = 0, a1 = 0, a2 = 0, a3 = 0, a4 = 0, a5 = 0, a6 = 0, a7 = 0;
#pragma unroll 8
  for (int l = 0; l < 32; ++l) {
    f32x4 x = __builtin_nontemporal_load((const f32x4*)(p + (size_t)l * DD));
    f32x4 y = __builtin_nontemporal_load((const f32x4*)(p + (size_t)l * DD + 4));
    a0 += x[0]; a1 += x[1]; a2 += x[2]; a3 += x[3];
    a4 += y[0]; a5 += y[1]; a6 += y[2]; a7 += y[3];
  }
  f32x4 o0 = {a0, a1, a2, a3}, o1 = {a4, a5, a6, a7};
  *(f32x4*)&sm.red[w][c8] = o0;
  *(f32x4*)&sm.red[w][c8 + 4] = o1;
  __syncthreads();
#pragma unroll
  for (int t = 0; t < 2; ++t) {
    int c = tid * 2 + t;
    float s = sm.red[0][c] + sm.red[1][c] + sm.red[2][c] + sm.red[3][c];
    part[((size_t)b * 32 + lc) * DD + c] = s;
  }
}

// ------- K3: partial projections: sq@Wq, sk@Wk, bv@Wo (24 blocks) -------
__global__ __launch_bounds__(256) void k_proj(
    const float* __restrict__ qpart, const float* __restrict__ kpart,
    const float* __restrict__ Wq, const float* __restrict__ Wk,
    const float* __restrict__ bv, const float* __restrict__ Wo,
    float* __restrict__ partQ, float* __restrict__ partK,
    float* __restrict__ partO) {
  __shared__ float ss[BB][64];
  int bid = blockIdx.x;
  int tid = threadIdx.x;
  int jc = bid & 7, which = bid >> 3;
  int j0 = jc * 64;
  if (which == 2) {
    float a0 = 0.f, a1 = 0.f;
    for (int j = 0; j < 64; ++j) {
      float b = bv[j0 + j];
      a0 += b * Wo[(size_t)(j0 + j) * DD + tid];
      a1 += b * Wo[(size_t)(j0 + j) * DD + tid + 256];
    }
    partO[(size_t)jc * DD + tid] = a0;
    partO[(size_t)jc * DD + tid + 256] = a1;
    return;
  }
  const float* part_in = which ? kpart : qpart;
  const float* W = which ? Wk : Wq;
  for (int e = tid; e < BB * 64; e += 256) {
    int b = e >> 6, j = e & 63;
    float s = 0.f;
#pragma unroll 8
    for (int p = 0; p < 32; ++p)
      s += part_in[((size_t)b * 32 + p) * DD + j0 + j];
    ss[b][j] = s;
  }
  __syncthreads();
  float a[BB][2];
#pragma unroll
  for (int b = 0; b < BB; ++b) { a[b][0] = 0.f; a[b][1] = 0.f; }
  for (int j = 0; j < 64; ++j) {
    float w0 = W[(size_t)(j0 + j) * DD + tid];
    float w1 = W[(size_t)(j0 + j) * DD + tid + 256];
#pragma unroll
    for (int b = 0; b < BB; ++b) {
      float sv = ss[b][j];
      a[b][0] += sv * w0;
      a[b][1] += sv * w1;
    }
  }
  float* part = which ? partK : partQ;
#pragma unroll
  for (int b = 0; b < BB; ++b) {
    part[((size_t)jc * BB + b) * DD + tid] = a[b][0];
    part[((size_t)jc * BB + b) * DD + tid + 256] = a[b][1];
  }
}

// ------- K4: reduce proj partials, mean_value, top-41, softmax, bvo -------
__global__ __launch_bounds__(512) void k_stats2(
    const float* __restrict__ partQ, const float* __restrict__ partK,
    const float* __restrict__ partO,
    const float* __restrict__ bq, const float* __restrict__ bk,
    const float* __restrict__ bo,
    int* __restrict__ idx_out, float* __restrict__ wts_out,
    float* __restrict__ bvo_out) {
  __shared__ float Sq[BB][DD];
  __shared__ float Sk[BB][DD];
  __shared__ float mvs[BB][64];
  __shared__ float mab[64];
  __shared__ int idxs[64];
  int tid = threadIdx.x;
  float bqv = bq[tid] * (float)LL, bkv = bk[tid] * (float)LL;
#pragma unroll
  for (int b = 0; b < BB; ++b) {
    float aq = 0.f, ak = 0.f;
#pragma unroll
    for (int jc = 0; jc < 8; ++jc) {
      aq += partQ[((size_t)jc * BB + b) * DD + tid];
      ak += partK[((size_t)jc * BB + b) * DD + tid];
    }
    Sq[b][tid] = aq + bqv;
    Sk[b][tid] = ak + bkv;
  }
  {
    float ao = 0.f;
#pragma unroll
    for (int jc = 0; jc < 8; ++jc) ao += partO[(size_t)jc * DD + tid];
    bvo_out[tid] = ao + bo[tid];
  }
  __syncthreads();
  {
    int b = tid >> 6, d = tid & 63;
    float s = 0.f;
#pragma unroll
    for (int h = 0; h < 8; ++h) s += Sq[b][h * 64 + d] * Sk[b][h * 64 + d];
    mvs[b][d] = s * (1.0f / ((float)LL * 8.0f));
  }
  __syncthreads();
  if (tid < 64) {
    float s = 0.f;
#pragma unroll
    for (int b = 0; b < BB; ++b) s += mvs[b][tid];
    mab[tid] = s * 0.125f;
  }
  __syncthreads();
  if (tid < 64) {
    float x = mab[tid];
    int r = 0;
    for (int d = 0; d < 64; ++d) {
      float y = mab[d];
      r += (y > x || (y == x && d < tid)) ? 1 : 0;
    }
    if (r < KSEL) { idxs[r] = tid; idx_out[r] = tid; }
  }
  __syncthreads();
  if (tid < BB) {
    int b = tid;
    float mx = -3.4e38f;
    for (int i = 0; i < KSEL; ++i) mx = fmaxf(mx, mvs[b][idxs[i]]);
    float s = 0.f;
    for (int i = 0; i < KSEL; ++i) s += expf(mvs[b][idxs[i]] - mx);
    float inv = 1.f / s;
    for (int i = 0; i < KSEL; ++i) wts_out[b * 64 + i] = expf(mvs[b][idxs[i]] - mx) * inv;
  }
}

// -------- K5: out[64 x 128ch] = M[64x128] @ Pwin[128 x 128ch] + bvo (f32 out) --------
__global__ __launch_bounds__(256) void k_convp(const ushort* __restrict__ P,
                                               const int* __restrict__ idx,
                                               const float* __restrict__ wts,
                                               const float* __restrict__ bvo,
                                               float* __restrict__ C) {
  __shared__ ushort pwinT[128 * 136];  // [c][j]
  __shared__ ushort Mlds[64 * 136];    // [r][j]
  __shared__ float coefw[256];
  int lt = blockIdx.x;
  int ch0 = blockIdx.y * 128;
  int b = blockIdx.z;
  int tid = threadIdx.x;
  int l0 = lt * 64;

  coefw[tid] = 0.f;
  __syncthreads();
  if (tid < KSEL) coefw[64 + idx[tid]] = wts[b * 64 + tid];
  __syncthreads();

  // stage Pwin^T: thread owns 2 channels (c2, c2+1), 32 j's
  {
    int c2 = (tid & 63) * 2;
    int jh = tid >> 6;  // 0..3
    const ushort* Pb = P + (size_t)b * LL * DD + ch0 + c2;
    unsigned int pk[32];
#pragma unroll
    for (int jj = 0; jj < 32; ++jj) {
      int ja = (l0 + jh * 32 + jj) & (LL - 1);
      pk[jj] = *(const unsigned int*)&Pb[(size_t)ja * DD];
    }
#pragma unroll
    for (int qq = 0; qq < 4; ++qq) {
      union { ushort us[8]; short8 s; } lo, hi;
#pragma unroll
      for (int i = 0; i < 8; ++i) {
        lo.us[i] = (ushort)(pk[qq * 8 + i] & 0xffffu);
        hi.us[i] = (ushort)(pk[qq * 8 + i] >> 16);
      }
      *(short8*)&pwinT[c2 * 136 + jh * 32 + qq * 8] = lo.s;
      *(short8*)&pwinT[(c2 + 1) * 136 + jh * 32 + qq * 8] = hi.s;
    }
  }
  // build M[r][j] = bf16(coefw[64 + j - r])
#pragma unroll
  for (int it = 0; it < 8; ++it) {
    int e = (it * 256 + tid) * 4;
    int r = e >> 7, j0 = e & 127;
    ushort4 m4;
    m4.x = f2bf(coefw[64 + j0 + 0 - r]);
    m4.y = f2bf(coefw[64 + j0 + 1 - r]);
    m4.z = f2bf(coefw[64 + j0 + 2 - r]);
    m4.w = f2bf(coefw[64 + j0 + 3 - r]);
    *(ushort4*)&Mlds[r * 136 + j0] = m4;
  }
  __syncthreads();

  int lane = tid & 63, w = tid >> 6;
  int r15 = lane & 15, g = lane >> 4;
  f32x4 acc[4][2] = {};
#pragma unroll
  for (int ks = 0; ks < 4; ++ks) {
    int kc = ks * 4 + g;
    short8 av[4], bvv[2];
#pragma unroll
    for (int m = 0; m < 4; ++m)
      av[m] = *(const short8*)&Mlds[(m * 16 + r15) * 136 + kc * 8];
#pragma unroll
    for (int n = 0; n < 2; ++n)
      bvv[n] = *(const short8*)&pwinT[(w * 32 + n * 16 + r15) * 136 + kc * 8];
#pragma unroll
    for (int m = 0; m < 4; ++m)
#pragma unroll
      for (int n = 0; n < 2; ++n)
        acc[m][n] = __builtin_amdgcn_mfma_f32_16x16x32_bf16(av[m], bvv[n], acc[m][n], 0, 0, 0);
  }

  float* Cb = C + ((size_t)b * LL + l0) * DD + ch0;
#pragma unroll
  for (int n = 0; n < 2; ++n) {
    int col = w * 32 + n * 16 + r15;
    float bc = bvo[ch0 + col];
#pragma unroll
    for (int m = 0; m < 4; ++m) {
      int row = m * 16 + g * 4;
#pragma unroll
      for (int r = 0; r < 4; ++r)
        Cb[(size_t)(row + r) * DD + col] = acc[m][n][r] + bc;
    }
  }
}

extern "C" void kernel_launch(void* const* d_in, const int* in_sizes, int n_in,
                              void* d_out, int out_size, void* d_ws, size_t ws_size,
                              hipStream_t stream) {
  const float* q  = (const float*)d_in[0];
  const float* k  = (const float*)d_in[1];
  const float* v  = (const float*)d_in[2];
  const float* Wq = (const float*)d_in[3];
  const float* bq = (const float*)d_in[4];
  const float* Wk = (const float*)d_in[5];
  const float* bk = (const float*)d_in[6];
  const float* Wv = (const float*)d_in[7];
  const float* bv = (const float*)d_in[8];
  const float* Wo = (const float*)d_in[9];
  const float* bo = (const float*)d_in[10];
  float* out = (float*)d_out;

  char* ws = (char*)d_ws;
  ushort* P     = (ushort*)(ws + 0x0);        // 32 MB bf16 [B*L*D] = v @ Wvo
  ushort* wvot  = (ushort*)(ws + 0x2000000);  // 512 KB bf16 WvoT
  float* qpart  = (float*)(ws + 0x2080000);   // 512 KB [8][32][512]
  float* kpart  = (float*)(ws + 0x2100000);   // 512 KB
  float* partQ  = (float*)(ws + 0x2180000);   // 128 KB
  float* partK  = (float*)(ws + 0x21A0000);   // 128 KB
  float* partO  = (float*)(ws + 0x21C0000);   // 16 KB
  int*   idx    = (int*)(ws + 0x21C8000);     // 256 B
  float* wts    = (float*)(ws + 0x21C9000);   // 2 KB
  float* bvo    = (float*)(ws + 0x21CA000);   // 2 KB

  k_wvot<<<dim3(2, 64), 256, 0, stream>>>(Wv, Wo, wvot);
  k_fused<<<dim3(1536), 256, 0, stream>>>(q, k, v, wvot, P, qpart, kpart);
  k_proj<<<dim3(24), 256, 0, stream>>>(qpart, kpart, Wq, Wk, bv, Wo, partQ, partK, partO);
  k_stats2<<<dim3(1), 512, 0, stream>>>(partQ, partK, partO, bq, bk, bo, idx, wts, bvo);
  k_convp<<<dim3(64, 4, 8), 256, 0, stream>>>(P, idx, wts, bvo, out);
}